// Round 14
// baseline (73.176 us; speedup 1.0000x reference)
//
#include <hip/hip_runtime.h>
#include <hip/hip_bf16.h>

typedef __bf16 bf16x8 __attribute__((ext_vector_type(8)));
typedef float  f32x4  __attribute__((ext_vector_type(4)));

constexpr int B = 8, N = 4096, T = 128, D = 32;
constexpr float GAMMA = 0.001f;
constexpr float LOG2E = 1.4426950408889634f;
constexpr float K2 = -GAMMA * LOG2E;   // coeff on sq1 / sq2 (log2 domain)
constexpr float M2 = -2.0f * K2;       // coeff on dot

__device__ __forceinline__ float exp2_fast(float t) {
#if __has_builtin(__builtin_amdgcn_exp2f)
  return __builtin_amdgcn_exp2f(t);
#else
  return exp2f(t);
#endif
}

// deg-3 minimax for 2^t on [-2, 0]; abs err ~6.5e-4 (t provably in-range).
__device__ __forceinline__ float exp2_poly(float t) {
  return fmaf(fmaf(fmaf(0.0285860f, t, 0.2107500f), t, 0.6821055f), t,
              0.9993455f);
}

// ---------------------------------------------------------------------------
// Kernel 1 (MFMA proj): unchanged from r3-r13 (~5 us).
// ---------------------------------------------------------------------------
__global__ __launch_bounds__(256, 2) void proj_mfma(
    const float* __restrict__ x,  const float* __restrict__ W1,
    const float* __restrict__ b1, const float* __restrict__ W2,
    const float* __restrict__ b2,
    __bf16* __restrict__ p1b, __bf16* __restrict__ p2b,
    float* __restrict__ s1, float* __restrict__ e2) {
  __shared__ bf16x8 wlds[4][4][64];   // 16 KB, frag-ready
  const int tid  = threadIdx.x;
  const int lane = tid & 63;
  const int wid  = tid >> 6;
  const int lr   = lane & 15;
  const int lk   = lane >> 4;
  const int r0   = blockIdx.x * 64 + wid * 16;   // 0 .. B*N-1

  #pragma unroll
  for (int t = 0; t < 4; ++t) {
    const int e  = tid + t * 256;
    const int c  = e >> 8;
    const int s  = (e >> 6) & 3;
    const int ln = e & 63;
    const int llr = ln & 15, llk = ln >> 4;
    const float* Wp = (c < 2) ? W1 : W2;
    const int cc = (c * 16 + llr) & 31;
    bf16x8 v;
    #pragma unroll
    for (int j = 0; j < 8; ++j)
      v[j] = (__bf16)Wp[(s * 32 + llk * 8 + j) * D + cc];
    wlds[c][s][ln] = v;
  }
  __syncthreads();

  bf16x8 wf[4][4];
  #pragma unroll
  for (int c = 0; c < 4; ++c)
    #pragma unroll
    for (int s = 0; s < 4; ++s)
      wf[c][s] = wlds[c][s][lane];

  bf16x8 af[4];
  const float* xr = x + (size_t)(r0 + lr) * T;
  #pragma unroll
  for (int s = 0; s < 4; ++s) {
    const int t0 = s * 32 + lk * 8;
    const f32x4 v0 = *reinterpret_cast<const f32x4*>(xr + t0);
    const f32x4 v1 = *reinterpret_cast<const f32x4*>(xr + t0 + 4);
    #pragma unroll
    for (int j = 0; j < 4; ++j) {
      af[s][j]     = (__bf16)v0[j];
      af[s][4 + j] = (__bf16)v1[j];
    }
  }

  f32x4 pv[4];
  #pragma unroll
  for (int c = 0; c < 4; ++c) {
    const float* bp = (c < 2) ? b1 : b2;
    const float bv = bp[(c * 16 + lr) & 31];
    f32x4 accv = {bv, bv, bv, bv};
    #pragma unroll
    for (int s = 0; s < 4; ++s)
      accv = __builtin_amdgcn_mfma_f32_16x16x32_bf16(af[s], wf[c][s], accv, 0, 0, 0);
    pv[c] = accv;
  }

  #pragma unroll
  for (int c = 0; c < 2; ++c)
    #pragma unroll
    for (int r = 0; r < 4; ++r)
      p1b[(size_t)(r0 + lk * 4 + r) * D + c * 16 + lr] = (__bf16)(M2 * pv[c][r]);
  #pragma unroll
  for (int c = 2; c < 4; ++c)
    #pragma unroll
    for (int r = 0; r < 4; ++r)
      p2b[(size_t)(r0 + lk * 4 + r) * D + (c - 2) * 16 + lr] = (__bf16)pv[c][r];

  float q1[4], q2[4];
  #pragma unroll
  for (int r = 0; r < 4; ++r) {
    q1[r] = fmaf(pv[0][r], pv[0][r], pv[1][r] * pv[1][r]);
    q2[r] = fmaf(pv[2][r], pv[2][r], pv[3][r] * pv[3][r]);
  }
  #pragma unroll
  for (int m = 1; m < 16; m <<= 1)
    #pragma unroll
    for (int r = 0; r < 4; ++r) {
      q1[r] += __shfl_xor(q1[r], m, 64);
      q2[r] += __shfl_xor(q2[r], m, 64);
    }
  if (lr == 0) {
    #pragma unroll
    for (int r = 0; r < 4; ++r) {
      const int row = r0 + lk * 4 + r;
      s1[row] = K2 * q1[r];
      e2[row] = 0.125f * exp2_fast(K2 * q2[r]);
    }
  }
}

// ---------------------------------------------------------------------------
// Kernel 2 v14: zero-barrier zero-LDS persistent-wave pipeline.
// One 64-thread block = one wave owning a 32-row strip x 128-col chunk.
// A-frags + S (mfma C-in) for all 8 batches live in registers; 8 j-steps of
// 16 cols sweep with 1-deep named-prefetch (r4's clean fx/fy idiom) of
// B-frags + E from global (L2-hot: same-jc blocks share an XCD).
// Stores are issued per-step -> write drain overlaps compute continuously;
// no __syncthreads anywhere -> no phase lockstep (r9-r11's ~30us floor).
// ---------------------------------------------------------------------------
struct Frag {
  bf16x8 Bv[B];
  float  Ev[B];
};

__global__ __launch_bounds__(64, 2) void fused_kernel(
    const __bf16* __restrict__ p1b, const __bf16* __restrict__ p2b,
    const float* __restrict__ s1,   const float* __restrict__ e2,
    float* __restrict__ out) {
  const int lane = threadIdx.x;        // 0..63
  const int bid  = blockIdx.x;         // 4096 blocks
  const int is   = bid & 127;          // row strip (consecutive bids spread
  const int jc   = bid >> 7;           //  across XCDs within one j-chunk)
  const int i0   = is * 32;
  const int jb   = jc * 128;
  const int lr = lane & 15;
  const int lk = lane >> 4;

  // persistent per-wave state: A-frags + S (C-in) for all batches
  bf16x8 A[B][2];
  f32x4  S[B][2];
  #pragma unroll
  for (int b = 0; b < B; ++b) {
    #pragma unroll
    for (int a = 0; a < 2; ++a) {
      A[b][a] = *reinterpret_cast<const bf16x8*>(
          p1b + ((size_t)b * N + i0 + a * 16 + lr) * D + lk * 8);
      S[b][a] = *reinterpret_cast<const f32x4*>(
          s1 + (size_t)b * N + i0 + a * 16 + lk * 4);
    }
  }

  Frag fx, fy;

  auto load = [&](Frag& f, int st) __attribute__((always_inline)) {
    const int jj = jb + st * 16;
    #pragma unroll
    for (int b = 0; b < B; ++b) {
      f.Bv[b] = *reinterpret_cast<const bf16x8*>(
          p2b + ((size_t)b * N + jj + lr) * D + lk * 8);
      f.Ev[b] = e2[(size_t)b * N + jj + lr];
    }
  };

  auto computeStore = [&](const Frag& f, int st) __attribute__((always_inline)) {
    const int jj = jb + st * 16;
    f32x4 acc0 = {0.f, 0.f, 0.f, 0.f};
    f32x4 acc1 = {0.f, 0.f, 0.f, 0.f};
    #pragma unroll
    for (int b = 0; b < B; ++b) {
      f32x4 t0 = __builtin_amdgcn_mfma_f32_16x16x32_bf16(
          A[b][0], f.Bv[b], S[b][0], 0, 0, 0);
      #pragma unroll
      for (int r = 0; r < 4; ++r)
        acc0[r] = fmaf(f.Ev[b], exp2_poly(t0[r]), acc0[r]);
      f32x4 t1 = __builtin_amdgcn_mfma_f32_16x16x32_bf16(
          A[b][1], f.Bv[b], S[b][1], 0, 0, 0);
      #pragma unroll
      for (int r = 0; r < 4; ++r)
        acc1[r] = fmaf(f.Ev[b], exp2_poly(t1[r]), acc1[r]);
    }
    const bool hasdiag = (jj < i0 + 32) && (i0 < jj + 16);
    const int col = jj + lr;
    #pragma unroll
    for (int r = 0; r < 4; ++r) {
      const int row0 = i0 + lk * 4 + r;
      float v0 = acc0[r];
      if (hasdiag && row0 == col) v0 = 0.1f;
      out[(size_t)row0 * N + col] = v0;
    }
    #pragma unroll
    for (int r = 0; r < 4; ++r) {
      const int row1 = i0 + 16 + lk * 4 + r;
      float v1 = acc1[r];
      if (hasdiag && row1 == col) v1 = 0.1f;
      out[(size_t)row1 * N + col] = v1;
    }
  };

  // 8 j-steps, 1-deep software pipeline (all indices compile-time)
  load(fx, 0);
  load(fy, 1); computeStore(fx, 0);
  load(fx, 2); computeStore(fy, 1);
  load(fy, 3); computeStore(fx, 2);
  load(fx, 4); computeStore(fy, 3);
  load(fy, 5); computeStore(fx, 4);
  load(fx, 6); computeStore(fy, 5);
  load(fy, 7); computeStore(fx, 6);
  computeStore(fy, 7);
}

extern "C" void kernel_launch(void* const* d_in, const int* in_sizes, int n_in,
                              void* d_out, int out_size, void* d_ws, size_t ws_size,
                              hipStream_t stream) {
  (void)in_sizes; (void)n_in; (void)out_size; (void)ws_size;
  const float* x  = (const float*)d_in[0];
  const float* W1 = (const float*)d_in[1];
  const float* b1 = (const float*)d_in[2];
  const float* W2 = (const float*)d_in[3];
  const float* b2 = (const float*)d_in[4];
  float* out = (float*)d_out;

  char* ws = (char*)d_ws;
  const size_t pbytes = (size_t)B * N * D * sizeof(__bf16);  // 2 MB each
  __bf16* p1b = (__bf16*)ws;
  __bf16* p2b = (__bf16*)(ws + pbytes);
  float*  s1  = (float*)(ws + 2 * pbytes);
  float*  e2  = (float*)(ws + 2 * pbytes + (size_t)B * N * sizeof(float));

  proj_mfma<<<(B * N) / 64, 256, 0, stream>>>(x, W1, b1, W2, b2, p1b, p2b, s1, e2);

  fused_kernel<<<(N / 32) * (N / 128), 64, 0, stream>>>(p1b, p2b, s1, e2, out);
}

// Round 15
// 63.371 us; speedup vs baseline: 1.1547x; 1.1547x over previous
//
#include <hip/hip_runtime.h>
#include <hip/hip_bf16.h>

typedef __bf16 bf16x8 __attribute__((ext_vector_type(8)));
typedef float  f32x4  __attribute__((ext_vector_type(4)));

constexpr int B = 8, N = 4096, T = 128, D = 32;
constexpr float GAMMA = 0.001f;
constexpr float LOG2E = 1.4426950408889634f;
constexpr float K2 = -GAMMA * LOG2E;   // coeff on sq1 / sq2 (log2 domain)
constexpr float M2 = -2.0f * K2;       // coeff on dot

__device__ __forceinline__ float exp2_fast(float t) {
#if __has_builtin(__builtin_amdgcn_exp2f)
  return __builtin_amdgcn_exp2f(t);
#else
  return exp2f(t);
#endif
}

// deg-3 minimax for 2^t on [-2, 0]; abs err ~6.5e-4 (t provably in-range).
__device__ __forceinline__ float exp2_poly(float t) {
  return fmaf(fmaf(fmaf(0.0285860f, t, 0.2107500f), t, 0.6821055f), t,
              0.9993455f);
}

// ---------------------------------------------------------------------------
// Kernel 1 (MFMA proj): unchanged from r3-r14 (~5 us).
// ---------------------------------------------------------------------------
__global__ __launch_bounds__(256, 2) void proj_mfma(
    const float* __restrict__ x,  const float* __restrict__ W1,
    const float* __restrict__ b1, const float* __restrict__ W2,
    const float* __restrict__ b2,
    __bf16* __restrict__ p1b, __bf16* __restrict__ p2b,
    float* __restrict__ s1, float* __restrict__ e2) {
  __shared__ bf16x8 wlds[4][4][64];   // 16 KB, frag-ready
  const int tid  = threadIdx.x;
  const int lane = tid & 63;
  const int wid  = tid >> 6;
  const int lr   = lane & 15;
  const int lk   = lane >> 4;
  const int r0   = blockIdx.x * 64 + wid * 16;   // 0 .. B*N-1

  #pragma unroll
  for (int t = 0; t < 4; ++t) {
    const int e  = tid + t * 256;
    const int c  = e >> 8;
    const int s  = (e >> 6) & 3;
    const int ln = e & 63;
    const int llr = ln & 15, llk = ln >> 4;
    const float* Wp = (c < 2) ? W1 : W2;
    const int cc = (c * 16 + llr) & 31;
    bf16x8 v;
    #pragma unroll
    for (int j = 0; j < 8; ++j)
      v[j] = (__bf16)Wp[(s * 32 + llk * 8 + j) * D + cc];
    wlds[c][s][ln] = v;
  }
  __syncthreads();

  bf16x8 wf[4][4];
  #pragma unroll
  for (int c = 0; c < 4; ++c)
    #pragma unroll
    for (int s = 0; s < 4; ++s)
      wf[c][s] = wlds[c][s][lane];

  bf16x8 af[4];
  const float* xr = x + (size_t)(r0 + lr) * T;
  #pragma unroll
  for (int s = 0; s < 4; ++s) {
    const int t0 = s * 32 + lk * 8;
    const f32x4 v0 = *reinterpret_cast<const f32x4*>(xr + t0);
    const f32x4 v1 = *reinterpret_cast<const f32x4*>(xr + t0 + 4);
    #pragma unroll
    for (int j = 0; j < 4; ++j) {
      af[s][j]     = (__bf16)v0[j];
      af[s][4 + j] = (__bf16)v1[j];
    }
  }

  f32x4 pv[4];
  #pragma unroll
  for (int c = 0; c < 4; ++c) {
    const float* bp = (c < 2) ? b1 : b2;
    const float bv = bp[(c * 16 + lr) & 31];
    f32x4 accv = {bv, bv, bv, bv};
    #pragma unroll
    for (int s = 0; s < 4; ++s)
      accv = __builtin_amdgcn_mfma_f32_16x16x32_bf16(af[s], wf[c][s], accv, 0, 0, 0);
    pv[c] = accv;
  }

  #pragma unroll
  for (int c = 0; c < 2; ++c)
    #pragma unroll
    for (int r = 0; r < 4; ++r)
      p1b[(size_t)(r0 + lk * 4 + r) * D + c * 16 + lr] = (__bf16)(M2 * pv[c][r]);
  #pragma unroll
  for (int c = 2; c < 4; ++c)
    #pragma unroll
    for (int r = 0; r < 4; ++r)
      p2b[(size_t)(r0 + lk * 4 + r) * D + (c - 2) * 16 + lr] = (__bf16)pv[c][r];

  float q1[4], q2[4];
  #pragma unroll
  for (int r = 0; r < 4; ++r) {
    q1[r] = fmaf(pv[0][r], pv[0][r], pv[1][r] * pv[1][r]);
    q2[r] = fmaf(pv[2][r], pv[2][r], pv[3][r] * pv[3][r]);
  }
  #pragma unroll
  for (int m = 1; m < 16; m <<= 1)
    #pragma unroll
    for (int r = 0; r < 4; ++r) {
      q1[r] += __shfl_xor(q1[r], m, 64);
      q2[r] += __shfl_xor(q2[r], m, 64);
    }
  if (lr == 0) {
    #pragma unroll
    for (int r = 0; r < 4; ++r) {
      const int row = r0 + lk * 4 + r;
      s1[row] = K2 * q1[r];
      e2[row] = 0.125f * exp2_fast(K2 * q2[r]);
    }
  }
}

// ---------------------------------------------------------------------------
// Kernel 2 v15: zero-barrier, zero-LDS, all-register; one wave = 16x64 tile.
//  - Two 4-batch passes: ~40 independent VMEM loads up-front per pass (one
//    amortized latency drain), then pure register MFMA+poly. Peak ~140 VGPR,
//    all statically indexed (no lambdas capturing arrays - r3/r12 trap).
//  - NO __syncthreads anywhere: no phase lockstep, no store-queue drain;
//    16384 waves retire in staggered generations -> store drain overlaps
//    other waves' compute continuously.
//  - Store pattern: r11's line-completing bursts (64-col tile: each 128B
//    output line fully written within one wave's 16-instr burst). r13/r14
//    counters proved partial-line patterns cost 2-3x HBM write volume.
//  - Consecutive bids share the 32KB B-panel (is in low bits) -> L1/L2 hot.
// ---------------------------------------------------------------------------
__global__ __launch_bounds__(64, 2) void fused_kernel(
    const __bf16* __restrict__ p1b, const __bf16* __restrict__ p2b,
    const float* __restrict__ s1,   const float* __restrict__ e2,
    float* __restrict__ out) {
  const int lane = threadIdx.x;        // 0..63
  const int bid  = blockIdx.x;         // 16384 blocks
  const int is   = bid & 255;          // row strip (low bits: same-jc
  const int jc   = bid >> 8;           //  neighbors share the B panel)
  const int i0   = is * 16;
  const int j0   = jc * 64;
  const int lr = lane & 15;
  const int lk = lane >> 4;

  f32x4 acc[4];
  #pragma unroll
  for (int c = 0; c < 4; ++c) acc[c] = f32x4{0.f, 0.f, 0.f, 0.f};

#define PASS(B0)                                                              \
  {                                                                           \
    bf16x8 A[4];                                                              \
    bf16x8 Bf[4][4];                                                          \
    f32x4  S[4];                                                              \
    float  E[4][4];                                                           \
    _Pragma("unroll")                                                         \
    for (int b4 = 0; b4 < 4; ++b4) {                                          \
      const size_t rb = (size_t)(B0 + b4) * N;                                \
      A[b4] = *reinterpret_cast<const bf16x8*>(                               \
          p1b + (rb + i0 + lr) * D + lk * 8);                                 \
      _Pragma("unroll")                                                       \
      for (int c = 0; c < 4; ++c)                                             \
        Bf[b4][c] = *reinterpret_cast<const bf16x8*>(                         \
            p2b + (rb + j0 + c * 16 + lr) * D + lk * 8);                      \
      S[b4] = *reinterpret_cast<const f32x4*>(s1 + rb + i0 + lk * 4);         \
      _Pragma("unroll")                                                       \
      for (int c = 0; c < 4; ++c)                                             \
        E[b4][c] = e2[rb + j0 + c * 16 + lr];                                 \
    }                                                                         \
    _Pragma("unroll")                                                         \
    for (int b4 = 0; b4 < 4; ++b4) {                                          \
      _Pragma("unroll")                                                       \
      for (int c = 0; c < 4; ++c) {                                           \
        f32x4 t = __builtin_amdgcn_mfma_f32_16x16x32_bf16(                    \
            A[b4], Bf[b4][c], S[b4], 0, 0, 0);                                \
        _Pragma("unroll")                                                     \
        for (int r = 0; r < 4; ++r)                                           \
          acc[c][r] = fmaf(E[b4][c], exp2_poly(t[r]), acc[c][r]);             \
      }                                                                       \
    }                                                                         \
  }

  PASS(0)
  PASS(4)
#undef PASS

  const bool hasdiag = (i0 < j0 + 64) && (j0 < i0 + 16);
  #pragma unroll
  for (int c = 0; c < 4; ++c) {
    #pragma unroll
    for (int r = 0; r < 4; ++r) {
      const int row = i0 + lk * 4 + r;
      const int col = j0 + c * 16 + lr;
      float v = acc[c][r];
      if (hasdiag && row == col) v = 0.1f;
      out[(size_t)row * N + col] = v;
    }
  }
}

extern "C" void kernel_launch(void* const* d_in, const int* in_sizes, int n_in,
                              void* d_out, int out_size, void* d_ws, size_t ws_size,
                              hipStream_t stream) {
  (void)in_sizes; (void)n_in; (void)out_size; (void)ws_size;
  const float* x  = (const float*)d_in[0];
  const float* W1 = (const float*)d_in[1];
  const float* b1 = (const float*)d_in[2];
  const float* W2 = (const float*)d_in[3];
  const float* b2 = (const float*)d_in[4];
  float* out = (float*)d_out;

  char* ws = (char*)d_ws;
  const size_t pbytes = (size_t)B * N * D * sizeof(__bf16);  // 2 MB each
  __bf16* p1b = (__bf16*)ws;
  __bf16* p2b = (__bf16*)(ws + pbytes);
  float*  s1  = (float*)(ws + 2 * pbytes);
  float*  e2  = (float*)(ws + 2 * pbytes + (size_t)B * N * sizeof(float));

  proj_mfma<<<(B * N) / 64, 256, 0, stream>>>(x, W1, b1, W2, b2, p1b, p2b, s1, e2);

  fused_kernel<<<(N / 16) * (N / 64), 64, 0, stream>>>(p1b, p2b, s1, e2, out);
}

// Round 16
// 38.041 us; speedup vs baseline: 1.9236x; 1.6658x over previous
//
#include <hip/hip_runtime.h>
#include <hip/hip_bf16.h>

typedef __bf16 bf16x8 __attribute__((ext_vector_type(8)));
typedef float  f32x4  __attribute__((ext_vector_type(4)));

constexpr int B = 8, N = 4096, T = 128, D = 32;
constexpr float GAMMA = 0.001f;
constexpr float LOG2E = 1.4426950408889634f;
constexpr float K2 = -GAMMA * LOG2E;   // coeff on sq1 / sq2 (log2 domain)
constexpr float M2 = -2.0f * K2;       // coeff on dot

__device__ __forceinline__ float exp2_fast(float t) {
#if __has_builtin(__builtin_amdgcn_exp2f)
  return __builtin_amdgcn_exp2f(t);
#else
  return exp2f(t);
#endif
}

// deg-3 minimax for 2^t on [-2, 0]; abs err ~6.5e-4 (t provably in-range).
constexpr float PC3 = 0.0285860f, PC2 = 0.2107500f, PC1 = 0.6821055f,
                PC0 = 0.9993455f;

__device__ __forceinline__ f32x4 fma4(f32x4 a, f32x4 b, f32x4 c) {
#if __has_builtin(__builtin_elementwise_fma)
  return __builtin_elementwise_fma(a, b, c);
#else
  f32x4 r;
  #pragma unroll
  for (int i = 0; i < 4; ++i) r[i] = fmaf(a[i], b[i], c[i]);
  return r;
#endif
}

__device__ __forceinline__ f32x4 splat4(float v) { return f32x4{v, v, v, v}; }

// vector poly on the native f32x4 MFMA output: lowers to v_pk_fma_f32 pairs
__device__ __forceinline__ f32x4 exp2_poly4(f32x4 t) {
  f32x4 q = fma4(splat4(PC3), t, splat4(PC2));
  q = fma4(q, t, splat4(PC1));
  q = fma4(q, t, splat4(PC0));
  return q;
}

// ---------------------------------------------------------------------------
// Kernel 1 (MFMA proj): unchanged from r3-r15 (~5-7 us).
// ---------------------------------------------------------------------------
__global__ __launch_bounds__(256, 2) void proj_mfma(
    const float* __restrict__ x,  const float* __restrict__ W1,
    const float* __restrict__ b1, const float* __restrict__ W2,
    const float* __restrict__ b2,
    __bf16* __restrict__ p1b, __bf16* __restrict__ p2b,
    float* __restrict__ s1, float* __restrict__ e2) {
  __shared__ bf16x8 wlds[4][4][64];   // 16 KB, frag-ready
  const int tid  = threadIdx.x;
  const int lane = tid & 63;
  const int wid  = tid >> 6;
  const int lr   = lane & 15;
  const int lk   = lane >> 4;
  const int r0   = blockIdx.x * 64 + wid * 16;   // 0 .. B*N-1

  #pragma unroll
  for (int t = 0; t < 4; ++t) {
    const int e  = tid + t * 256;
    const int c  = e >> 8;
    const int s  = (e >> 6) & 3;
    const int ln = e & 63;
    const int llr = ln & 15, llk = ln >> 4;
    const float* Wp = (c < 2) ? W1 : W2;
    const int cc = (c * 16 + llr) & 31;
    bf16x8 v;
    #pragma unroll
    for (int j = 0; j < 8; ++j)
      v[j] = (__bf16)Wp[(s * 32 + llk * 8 + j) * D + cc];
    wlds[c][s][ln] = v;
  }
  __syncthreads();

  bf16x8 wf[4][4];
  #pragma unroll
  for (int c = 0; c < 4; ++c)
    #pragma unroll
    for (int s = 0; s < 4; ++s)
      wf[c][s] = wlds[c][s][lane];

  bf16x8 af[4];
  const float* xr = x + (size_t)(r0 + lr) * T;
  #pragma unroll
  for (int s = 0; s < 4; ++s) {
    const int t0 = s * 32 + lk * 8;
    const f32x4 v0 = *reinterpret_cast<const f32x4*>(xr + t0);
    const f32x4 v1 = *reinterpret_cast<const f32x4*>(xr + t0 + 4);
    #pragma unroll
    for (int j = 0; j < 4; ++j) {
      af[s][j]     = (__bf16)v0[j];
      af[s][4 + j] = (__bf16)v1[j];
    }
  }

  f32x4 pv[4];
  #pragma unroll
  for (int c = 0; c < 4; ++c) {
    const float* bp = (c < 2) ? b1 : b2;
    const float bv = bp[(c * 16 + lr) & 31];
    f32x4 accv = {bv, bv, bv, bv};
    #pragma unroll
    for (int s = 0; s < 4; ++s)
      accv = __builtin_amdgcn_mfma_f32_16x16x32_bf16(af[s], wf[c][s], accv, 0, 0, 0);
    pv[c] = accv;
  }

  #pragma unroll
  for (int c = 0; c < 2; ++c)
    #pragma unroll
    for (int r = 0; r < 4; ++r)
      p1b[(size_t)(r0 + lk * 4 + r) * D + c * 16 + lr] = (__bf16)(M2 * pv[c][r]);
  #pragma unroll
  for (int c = 2; c < 4; ++c)
    #pragma unroll
    for (int r = 0; r < 4; ++r)
      p2b[(size_t)(r0 + lk * 4 + r) * D + (c - 2) * 16 + lr] = (__bf16)pv[c][r];

  float q1[4], q2[4];
  #pragma unroll
  for (int r = 0; r < 4; ++r) {
    q1[r] = fmaf(pv[0][r], pv[0][r], pv[1][r] * pv[1][r]);
    q2[r] = fmaf(pv[2][r], pv[2][r], pv[3][r] * pv[3][r]);
  }
  #pragma unroll
  for (int m = 1; m < 16; m <<= 1)
    #pragma unroll
    for (int r = 0; r < 4; ++r) {
      q1[r] += __shfl_xor(q1[r], m, 64);
      q2[r] += __shfl_xor(q2[r], m, 64);
    }
  if (lr == 0) {
    #pragma unroll
    for (int r = 0; r < 4; ++r) {
      const int row = r0 + lk * 4 + r;
      s1[row] = K2 * q1[r];
      e2[row] = 0.125f * exp2_fast(K2 * q2[r]);
    }
  }
}

// ---------------------------------------------------------------------------
// Kernel 2 v16 = r11's structure with two changes:
//  (1) LOOP INTERCHANGE: outer loop over output column PAIRS (cp), inner
//      over batches. Each cp's store burst (cols cp*32..cp*32+31, all 16
//      rows) completes 128B lines within one burst (no write amplification
//      - r13/r14's trap) and the cp=0 stores (32MB chip-wide) drain UNDER
//      cp=1's compute instead of clumping at kernel end.
//  (2) poly+accumulate vectorized on the native f32x4 MFMA output via
//      elementwise_fma -> v_pk_fma_f32 (VALU epilogue halved; unlike r6's
//      f32x2-extraction variant, no repacking moves needed).
// Everything else identical to r11 (read-once staging, swizzled B in LDS,
// A-frags in regs, grid 64x64, LB(256,4)).
// ---------------------------------------------------------------------------
__global__ __launch_bounds__(256, 4) void fused_kernel(
    const __bf16* __restrict__ p1b, const __bf16* __restrict__ p2b,
    const float* __restrict__ s1,   const float* __restrict__ e2,
    float* __restrict__ out) {
  __shared__ __align__(16) __bf16 LB[B * 64 * 32];  // 32 KB, swizzled slots
  __shared__ __align__(16) float  LS[B * 64];       // 2 KB
  __shared__ __align__(16) float  LE[B * 64];       // 2 KB

  const int tid  = threadIdx.x;
  const int lane = tid & 63;
  const int wid  = tid >> 6;
  const int j0 = blockIdx.x * 64;                // col base (block)
  const int i0blk = blockIdx.y * 64;             // row base (block)
  const int i0 = i0blk + wid * 16;               // row base (wave)
  const int lr = lane & 15;
  const int lk = lane >> 4;

  // A-fragments, all 8 batches (32 VGPR), issued first
  bf16x8 A[B];
  #pragma unroll
  for (int b = 0; b < B; ++b)
    A[b] = *reinterpret_cast<const bf16x8*>(
        p1b + ((size_t)b * N + i0 + lr) * D + lk * 8);

  // stage B tiles -> LDS (swizzled): 2048 16B-chunks, 8 per thread
  #pragma unroll
  for (int q = 0; q < 8; ++q) {
    const int g   = tid + q * 256;
    const int b   = g >> 8;
    const int c8  = g & 255;
    const int row = c8 >> 2;
    const int sl  = c8 & 3;
    const bf16x8 v = *reinterpret_cast<const bf16x8*>(
        p2b + ((size_t)b * N + j0 + row) * D + sl * 8);
    const int su = sl ^ ((row >> 1) & 3);
    *reinterpret_cast<bf16x8*>(&LB[(((b << 6) + row) << 2 | su) << 3]) = v;
  }
  // stage S (threads 0-127) and E (threads 128-255): 512 floats each
  if (tid < 128) {
    const int b = tid >> 4, o = (tid & 15) * 4;
    *reinterpret_cast<f32x4*>(&LS[b * 64 + o]) =
        *reinterpret_cast<const f32x4*>(s1 + (size_t)b * N + i0blk + o);
  } else {
    const int t2 = tid - 128;
    const int b = t2 >> 4, o = (t2 & 15) * 4;
    *reinterpret_cast<f32x4*>(&LE[b * 64 + o]) =
        *reinterpret_cast<const f32x4*>(e2 + (size_t)b * N + j0 + o);
  }

  __syncthreads();

  const int sub = lk ^ ((lr >> 1) & 3);   // B-read swizzle (c*16 keeps bits)

  #pragma unroll
  for (int cp = 0; cp < 2; ++cp) {
    const int c0 = cp * 2;
    const int c1 = cp * 2 + 1;

    f32x4 acc0 = {0.f, 0.f, 0.f, 0.f};
    f32x4 acc1 = {0.f, 0.f, 0.f, 0.f};

    #pragma unroll
    for (int b = 0; b < B; ++b) {
      const bf16x8 Bf0 = *reinterpret_cast<const bf16x8*>(
          &LB[(((b << 6) + c0 * 16 + lr) << 2 | sub) << 3]);
      const bf16x8 Bf1 = *reinterpret_cast<const bf16x8*>(
          &LB[(((b << 6) + c1 * 16 + lr) << 2 | sub) << 3]);
      const f32x4 S4 = *reinterpret_cast<const f32x4*>(
          &LS[b * 64 + wid * 16 + lk * 4]);

      const f32x4 t0 = __builtin_amdgcn_mfma_f32_16x16x32_bf16(
          A[b], Bf0, S4, 0, 0, 0);
      const f32x4 t1 = __builtin_amdgcn_mfma_f32_16x16x32_bf16(
          A[b], Bf1, S4, 0, 0, 0);

      acc0 = fma4(splat4(LE[b * 64 + c0 * 16 + lr]), exp2_poly4(t0), acc0);
      acc1 = fma4(splat4(LE[b * 64 + c1 * 16 + lr]), exp2_poly4(t1), acc1);
    }

    // store burst for this c-pair: cols cp*32 .. cp*32+31 of all 16 rows
    // -> every touched 128B line is fully written within this burst.
    const int col0 = j0 + c0 * 16 + lr;
    const int col1 = j0 + c1 * 16 + lr;
    #pragma unroll
    for (int r = 0; r < 4; ++r) {
      const int row = i0 + lk * 4 + r;
      float v0 = acc0[r];
      float v1 = acc1[r];
      if (row == col0) v0 = 0.1f;
      if (row == col1) v1 = 0.1f;
      out[(size_t)row * N + col0] = v0;
      out[(size_t)row * N + col1] = v1;
    }
  }
}

extern "C" void kernel_launch(void* const* d_in, const int* in_sizes, int n_in,
                              void* d_out, int out_size, void* d_ws, size_t ws_size,
                              hipStream_t stream) {
  (void)in_sizes; (void)n_in; (void)out_size; (void)ws_size;
  const float* x  = (const float*)d_in[0];
  const float* W1 = (const float*)d_in[1];
  const float* b1 = (const float*)d_in[2];
  const float* W2 = (const float*)d_in[3];
  const float* b2 = (const float*)d_in[4];
  float* out = (float*)d_out;

  char* ws = (char*)d_ws;
  const size_t pbytes = (size_t)B * N * D * sizeof(__bf16);  // 2 MB each
  __bf16* p1b = (__bf16*)ws;
  __bf16* p2b = (__bf16*)(ws + pbytes);
  float*  s1  = (float*)(ws + 2 * pbytes);
  float*  e2  = (float*)(ws + 2 * pbytes + (size_t)B * N * sizeof(float));

  proj_mfma<<<(B * N) / 64, 256, 0, stream>>>(x, W1, b1, W2, b2, p1b, p2b, s1, e2);

  dim3 grid(N / 64, N / 64);
  fused_kernel<<<grid, 256, 0, stream>>>(p1b, p2b, s1, e2, out);
}